// Round 3
// baseline (15222.702 us; speedup 1.0000x reference)
//
#include <hip/hip_runtime.h>
#include <math.h>

typedef float f4 __attribute__((ext_vector_type(4)));

#define NT 512
#define NH 1024
#define NHQ 256   // NH/4

// ws float offsets
#define H00 0
#define H01 32768
#define H10 65536
#define H11 98304
#define PLOG 131072      // 8192 floats
#define CTRS 139264      // uint region: arr[256] at stride 32 (8192), rel at +8192
#define X4OFF 147968
#define X4FLOATS (512u * 1024u * 32u)  // 64 MB

__device__ __forceinline__ void ld_cohx4(f4& d, const f4* p) {
  // coherent (MALL) 16B load, NOT serialized like volatile: manual waitcnt later
  asm volatile("global_load_dwordx4 %0, %1, off sc0 sc1" : "=v"(d) : "v"(p));
}
__device__ __forceinline__ void st_coh(float* p, float v) {
  __hip_atomic_store(p, v, __ATOMIC_RELAXED, __HIP_MEMORY_SCOPE_AGENT);
}
__device__ __forceinline__ float ld_cohf(const float* p) {
  return __hip_atomic_load(p, __ATOMIC_RELAXED, __HIP_MEMORY_SCOPE_AGENT);
}

__global__ __launch_bounds__(256) void init_kernel(const float* __restrict__ h0,
                                                   float* __restrict__ ws) {
  int g = blockIdx.x * 256 + threadIdx.x;  // 0..65535 == l*32768 + b*1024 + k
  int l = g >> 15;
  int b = (g >> 10) & 31;
  int k = g & 1023;
  size_t base = l ? (size_t)H11 : (size_t)H00;
  ws[base + (size_t)(k >> 2) * 128 + b * 4 + (k & 3)] = h0[g];
  if (g < 8448) ((unsigned*)(ws + CTRS))[g] = 0u;
}

__global__ __launch_bounds__(256) void xpose_kernel(const float* __restrict__ x,
                                                    float* __restrict__ ws) {
  f4* x4 = (f4*)(ws + X4OFF);
  const f4* xs = (const f4*)x;
  int t = blockIdx.x;             // 0..511
  int kqq = threadIdx.x >> 5;     // 0..7
  int b = threadIdx.x & 31;
  for (int i = 0; i < 32; ++i) {
    int kq = kqq * 32 + i;        // 0..255
    f4 v = xs[((size_t)b * NT + t) * NHQ + kq];
    x4[((size_t)t * NHQ + kq) * 32 + b] = v;   // coalesced write
  }
}

// Flag-based grid barrier: no RMW contention. Non-zero blocks store epoch r to
// a private slot; block 0 polls all slots (parallel across 255 threads), then
// stores the release flag; others poll it. All accesses agent-scope coherent.
__device__ __forceinline__ void gbar(unsigned* arr, unsigned* rel, unsigned r) {
  __syncthreads();  // compiler drains vmcnt before s_barrier -> h stores visible
  if (blockIdx.x == 0) {
    const int t = threadIdx.x;
    if (t >= 1 && t < 256) {
      while (__hip_atomic_load(&arr[t * 32], __ATOMIC_RELAXED,
                               __HIP_MEMORY_SCOPE_AGENT) < r)
        __builtin_amdgcn_s_sleep(1);
    }
    __syncthreads();
    if (t == 0)
      __hip_atomic_store(rel, r, __ATOMIC_RELAXED, __HIP_MEMORY_SCOPE_AGENT);
  } else {
    if (threadIdx.x == 0) {
      __hip_atomic_store(&arr[blockIdx.x * 32], r, __ATOMIC_RELAXED,
                         __HIP_MEMORY_SCOPE_AGENT);
      while (__hip_atomic_load(rel, __ATOMIC_RELAXED,
                               __HIP_MEMORY_SCOPE_AGENT) < r)
        __builtin_amdgcn_s_sleep(1);
    }
    __syncthreads();
  }
}

__global__ __launch_bounds__(512, 1) void rnn_kernel(
    const float* __restrict__ x,
    const float* __restrict__ Wih0, const float* __restrict__ Whh0,
    const float* __restrict__ bih0, const float* __restrict__ bhh0,
    const float* __restrict__ Wih1, const float* __restrict__ Whh1,
    const float* __restrict__ bih1, const float* __restrict__ bhh1,
    const float* __restrict__ Wcls, const float* __restrict__ bcls,
    float* __restrict__ out, float* ws, int use_x4) {
  const int bid = blockIdx.x;        // 0..255
  const int tid = threadIdx.x;       // 0..511
  const int b   = tid & 31;          // batch lane
  const int ks  = (tid >> 5) & 7;    // k-slice 0..7
  const int mh  = tid >> 8;          // matrix half: 0=input-side, 1=hidden-side
  const bool isL1 = (bid >= 128);
  const int jbase = (isL1 ? (bid - 128) : bid) * 8;

  f4* h0b0 = (f4*)(ws + H00); f4* h0b1 = (f4*)(ws + H01);
  f4* h1b0 = (f4*)(ws + H10); f4* h1b1 = (f4*)(ws + H11);
  float* plog = ws + PLOG;
  unsigned* arr = (unsigned*)(ws + CTRS);
  unsigned* rel = arr + 8192;
  const f4* x4p = (const f4*)(ws + X4OFF);

  __shared__ float part[4096];  // [slot 16][ji 8][b 32]

  const f4* wbase;
  if (!isL1) wbase = (const f4*)(mh == 0 ? Wih0 : Whh0) + (size_t)jbase * NHQ;
  else       wbase = (const f4*)(mh == 0 ? Wih1 : Whh1) + (size_t)jbase * NHQ;

  const int rj = tid >> 5;           // 0..7 (valid when tid<256)
  const int jout = jbase + rj;
  float bias = 0.f;
  if (tid < 256)
    bias = isL1 ? (bih1[jout] + bhh1[jout]) : (bih0[jout] + bhh0[jout]);

  float lg0 = 0.f, lg1 = 0.f;
  const int kq0 = ks * 32;

  for (int s = 0; s <= NT; ++s) {
    const int rp = s & 1;
    const bool active = isL1 ? (s >= 1) : (s < NT);
    if (active) {
      f4 acc[8];
      #pragma unroll
      for (int ji = 0; ji < 8; ++ji) acc[ji] = (f4)0.f;

      if (!isL1 && mh == 0) {
        if (use_x4) {
          const f4* sp = x4p + (size_t)s * 8192 + b;
          #pragma unroll 8
          for (int q = 0; q < 32; ++q) {
            f4 v = sp[(size_t)(kq0 + q) * 32];
            const f4* wb = wbase + kq0 + q;
            #pragma unroll
            for (int ji = 0; ji < 8; ++ji) acc[ji] += wb[(size_t)ji * NHQ] * v;
          }
        } else {
          const f4* sp = (const f4*)x + ((size_t)b * NT + s) * NHQ;
          #pragma unroll 8
          for (int q = 0; q < 32; ++q) {
            f4 v = sp[kq0 + q];
            const f4* wb = wbase + kq0 + q;
            #pragma unroll
            for (int ji = 0; ji < 8; ++ji) acc[ji] += wb[(size_t)ji * NHQ] * v;
          }
        }
      } else {
        const f4* hsrc;
        if (!isL1)        hsrc = rp ? h0b1 : h0b0;   // L0: h0 . Whh0
        else if (mh == 0) hsrc = rp ? h0b1 : h0b0;   // L1: y0 . Wih1
        else              hsrc = rp ? h1b1 : h1b0;   // L1: h1 . Whh1
        const f4* sp = hsrc + b + (size_t)kq0 * 32;
        f4 hA[16], hB[16];
        #pragma unroll
        for (int q = 0; q < 16; ++q) ld_cohx4(hA[q], sp + (size_t)q * 32);
        #pragma unroll
        for (int q = 0; q < 16; ++q) ld_cohx4(hB[q], sp + (size_t)(q + 16) * 32);
        asm volatile("s_waitcnt vmcnt(16)");   // batch A complete (in-order)
        __builtin_amdgcn_sched_barrier(0x74);  // block VALU hoist; let VMEM/SALU cross
        #pragma unroll
        for (int q = 0; q < 16; ++q) {
          const f4* wb = wbase + (kq0 + q);
          #pragma unroll
          for (int ji = 0; ji < 8; ++ji) acc[ji] += wb[(size_t)ji * NHQ] * hA[q];
        }
        asm volatile("s_waitcnt vmcnt(0)");    // batch B complete
        __builtin_amdgcn_sched_barrier(0x74);
        #pragma unroll
        for (int q = 0; q < 16; ++q) {
          const f4* wb = wbase + (kq0 + 16 + q);
          #pragma unroll
          for (int ji = 0; ji < 8; ++ji) acc[ji] += wb[(size_t)ji * NHQ] * hB[q];
        }
      }

      const int slot = mh * 8 + ks;  // 0..15
      #pragma unroll
      for (int ji = 0; ji < 8; ++ji)
        part[(slot * 8 + ji) * 32 + b] =
            (acc[ji][0] + acc[ji][1]) + (acc[ji][2] + acc[ji][3]);
      __syncthreads();

      if (tid < 256) {
        float sum = bias;
        #pragma unroll
        for (int r = 0; r < 16; ++r) sum += part[(r * 8 + rj) * 32 + b];
        float hv = tanhf(sum);
        float* dst;
        if (isL1) dst = (float*)(rp ? h1b0 : h1b1);   // write buf[rp^1]
        else      dst = (float*)(rp ? h0b0 : h0b1);
        st_coh(dst + (size_t)(jout >> 2) * 128 + b * 4 + (jout & 3), hv);
        if (isL1) {
          const int t = s - 1;
          lg0 = fmaf(hv, Wcls[(size_t)t * NH + jout], lg0);
          lg1 = fmaf(hv, Wcls[(size_t)524288 + (size_t)t * NH + jout], lg1);
          if (s == NT) out[64 + 32768 + (size_t)b * NH + jout] = hv;
        } else if (s == NT - 1) {
          out[64 + (size_t)b * NH + jout] = hv;
        }
      }
    }
    gbar(arr, rel, (unsigned)(s + 1));
  }

  // ---- epilogue: classifier reduction ----
  if (isL1 && tid < 256) {
    part[tid] = lg0;
    part[256 + tid] = lg1;
  }
  __syncthreads();
  if (isL1 && tid < 64) {
    const int c = tid >> 5, bb = tid & 31;
    float v = 0.f;
    #pragma unroll
    for (int ji = 0; ji < 8; ++ji) v += part[c * 256 + ji * 32 + bb];
    st_coh(&plog[(size_t)(bid - 128) * 64 + c * 32 + bb], v);
  }
  gbar(arr, rel, (unsigned)(NT + 2));
  if (bid == 0) {
    // 8192 plog values: [blk 128][pair 64]; block0's L2 is clean for plog ->
    // plain loads observe the sc1-written values via MALL.
    const int pair = tid & 63;
    const int bg = tid >> 6;           // 0..7
    float v = 0.f;
    #pragma unroll 4
    for (int blk = bg; blk < 128; blk += 8)
      v += plog[(size_t)blk * 64 + pair];
    part[tid] = v;
    __syncthreads();
    if (tid < 64) {
      float s2 = bcls[tid >> 5];
      #pragma unroll
      for (int g2 = 0; g2 < 8; ++g2) s2 += part[g2 * 64 + tid];
      out[(size_t)(tid & 31) * 2 + (tid >> 5)] = s2;  // logits [B,C]
    }
  }
}

extern "C" void kernel_launch(void* const* d_in, const int* in_sizes, int n_in,
                              void* d_out, int out_size, void* d_ws, size_t ws_size,
                              hipStream_t stream) {
  const float* x    = (const float*)d_in[0];
  const float* h0   = (const float*)d_in[1];
  const float* Wih0 = (const float*)d_in[2];
  const float* Whh0 = (const float*)d_in[3];
  const float* bih0 = (const float*)d_in[4];
  const float* bhh0 = (const float*)d_in[5];
  const float* Wih1 = (const float*)d_in[6];
  const float* Whh1 = (const float*)d_in[7];
  const float* bih1 = (const float*)d_in[8];
  const float* bhh1 = (const float*)d_in[9];
  const float* Wcls = (const float*)d_in[10];
  const float* bcls = (const float*)d_in[11];
  float* out = (float*)d_out;
  float* ws  = (float*)d_ws;

  int use_x4 = (ws_size >= ((size_t)X4OFF + X4FLOATS) * 4) ? 1 : 0;

  hipLaunchKernelGGL(init_kernel, dim3(256), dim3(256), 0, stream, h0, ws);
  if (use_x4)
    hipLaunchKernelGGL(xpose_kernel, dim3(512), dim3(256), 0, stream, x, ws);

  void* args[] = { (void*)&x, (void*)&Wih0, (void*)&Whh0, (void*)&bih0, (void*)&bhh0,
                   (void*)&Wih1, (void*)&Whh1, (void*)&bih1, (void*)&bhh1,
                   (void*)&Wcls, (void*)&bcls, (void*)&out, (void*)&ws, (void*)&use_x4 };
  hipLaunchCooperativeKernel((void*)rnn_kernel, dim3(256), dim3(512), args, 0, stream);
}

// Round 4
// 7891.306 us; speedup vs baseline: 1.9290x; 1.9290x over previous
//
#include <hip/hip_runtime.h>
#include <math.h>

typedef float f4 __attribute__((ext_vector_type(4)));

// ws float offsets
#define H00 0
#define H01 32768
#define H10 65536
#define H11 98304
#define PLOG 131072      // 8192 floats
#define FLAGS 139264     // 512 uints (256 used: [0..127]=L0, [128..255]=L1)
#define PRE  139776      // 512*32768 floats = 64 MB

__device__ __forceinline__ void ld_l2x4(f4& d, const f4* p) {
  // coherent-enough load: L1 bypass (sc0), L2 allowed (R2-validated path)
  asm volatile("global_load_dwordx4 %0, %1, off sc0" : "=v"(d) : "v"(p));
}
__device__ __forceinline__ void st_cohf(float* p, float v) {
  __hip_atomic_store(p, v, __ATOMIC_RELAXED, __HIP_MEMORY_SCOPE_AGENT);
}
__device__ __forceinline__ void st_cohu(unsigned* p, unsigned v) {
  __hip_atomic_store(p, v, __ATOMIC_RELAXED, __HIP_MEMORY_SCOPE_AGENT);
}
__device__ __forceinline__ unsigned ld_flag(const unsigned* p) {
  return __hip_atomic_load(p, __ATOMIC_RELAXED, __HIP_MEMORY_SCOPE_AGENT);
}

__global__ __launch_bounds__(256) void init_kernel(const float* __restrict__ h0,
                                                   float* __restrict__ ws) {
  int g = blockIdx.x * 256 + threadIdx.x;  // 0..65535 == l*32768 + b*1024 + k
  int l = g >> 15;
  int b = (g >> 10) & 31;
  int k = g & 1023;
  size_t base = l ? (size_t)H11 : (size_t)H00;
  ws[base + (size_t)(k >> 2) * 128 + b * 4 + (k & 3)] = h0[g];
  if (g < 512) ((unsigned*)(ws + FLAGS))[g] = 0u;
}

// pre[t, j, b] = sum_k x[b,t,k] * Wih0[j,k]   (biases added in-loop)
// grid 8192 = jq(16) * t(512), 256 threads = ks(8) x b(32)
__global__ __launch_bounds__(256) void pre_kernel(const float* __restrict__ x,
                                                  const float* __restrict__ W,
                                                  float* __restrict__ ws) {
  const int jq = blockIdx.x >> 9;      // 0..15
  const int t  = blockIdx.x & 511;
  const int ks = threadIdx.x >> 5;     // 0..7
  const int b  = threadIdx.x & 31;
  __shared__ float part[16][8][32];
  f4 xr[32];
  const f4* xp = (const f4*)x + ((size_t)b * 512 + t) * 256 + ks * 32;
  #pragma unroll
  for (int q = 0; q < 32; ++q) xr[q] = xp[q];
  f4* pre4 = (f4*)(ws + PRE + (size_t)t * 32768);
  for (int jt = 0; jt < 4; ++jt) {
    #pragma unroll 2
    for (int jj = 0; jj < 16; ++jj) {
      const int j = jq * 64 + jt * 16 + jj;
      const f4* wr = (const f4*)W + (size_t)j * 256 + ks * 32;
      f4 a = (f4)0.f;
      #pragma unroll
      for (int q = 0; q < 32; ++q) a += wr[q] * xr[q];
      part[jj][ks][b] = (a[0] + a[1]) + (a[2] + a[3]);
    }
    __syncthreads();
    if (threadIdx.x < 128) {
      const int jg4 = threadIdx.x >> 5;   // 0..3
      const int bb  = threadIdx.x & 31;
      f4 v;
      #pragma unroll
      for (int e = 0; e < 4; ++e) {
        float s = 0.f;
        #pragma unroll
        for (int k8 = 0; k8 < 8; ++k8) s += part[jg4 * 4 + e][k8][bb];
        v[e] = s;
      }
      pre4[(size_t)(jq * 16 + jt * 4 + jg4) * 32 + bb] = v;
    }
    __syncthreads();
  }
}

__global__ __launch_bounds__(512, 1) void rnn_kernel(
    const float* __restrict__ Whh0,
    const float* __restrict__ bih0, const float* __restrict__ bhh0,
    const float* __restrict__ Wih1, const float* __restrict__ Whh1,
    const float* __restrict__ bih1, const float* __restrict__ bhh1,
    const float* __restrict__ Wcls, const float* __restrict__ bcls,
    float* __restrict__ out, float* ws) {
  extern __shared__ float smem[];
  f4* w4 = (f4*)smem;                  // 4096 f4 = 64 KB
  float* part = smem + 16384;          // 4096 floats = 16 KB

  const int bid = blockIdx.x, tid = threadIdx.x;
  const int b = tid & 31, ks = (tid >> 5) & 7, mh = tid >> 8;
  const bool isL1 = bid >= 128;
  const int jbase = (isL1 ? bid - 128 : bid) * 8;

  unsigned* flags = (unsigned*)(ws + FLAGS);
  const int fidx = (tid < 256) ? (tid & 127) : (128 + (tid & 127));
  const int myflag = isL1 ? (128 + (bid - 128)) : bid;

  // LDS weight staging: L0 -> Whh0 slice; L1 -> Wih1 + Whh1 slices
  {
    const f4* sA = (const f4*)(isL1 ? Wih1 : Whh0) + (size_t)jbase * 256;
    for (int i = tid; i < 2048; i += 512) w4[i] = sA[i];
    if (isL1) {
      const f4* sB = (const f4*)Whh1 + (size_t)jbase * 256;
      for (int i = tid; i < 2048; i += 512) w4[2048 + i] = sB[i];
    }
  }

  // reduce-phase constants (tid < 256)
  const int rj = tid >> 5;             // 0..7 when tid<256
  const int jout = jbase + rj;
  float bias = 0.f;
  const float* preb = ws + PRE + ((jout >> 2) * 128 + b * 4 + (jout & 3));
  if (tid < 256)
    bias = isL1 ? (bih1[jout] + bhh1[jout]) : (bih0[jout] + bhh0[jout]);

  float lg0 = 0.f, lg1 = 0.f;
  __syncthreads();  // weights staged

  for (int s = 0; s <= 512; ++s) {
    if (s > 0) {  // distributed full grid barrier: wait everyone's epoch >= s
      const unsigned* fp = flags + fidx;
      while (!__all(ld_flag(fp) >= (unsigned)s)) {}
    }
    __syncthreads();
    __builtin_amdgcn_sched_barrier(0);

    const int rp = s & 1;
    const bool active = isL1 ? (s >= 1) : (s < 512);
    float pv = 0.f;
    if (!isL1 && tid < 256 && s < 512) pv = preb[(size_t)s * 32768];

    if (active) {
      f4 acc[8];
      #pragma unroll
      for (int ji = 0; ji < 8; ++ji) acc[ji] = (f4)0.f;

      if (!isL1) {
        // layer 0: h0 . Whh0, K split across mh halves (16 f4 each)
        const float* hb = rp ? ws + H01 : ws + H00;
        const int kb = mh * 128 + ks * 16;       // f4 index base
        const f4* sp = (const f4*)hb + b + (size_t)kb * 32;
        f4 hA[16];
        #pragma unroll
        for (int q = 0; q < 16; ++q) ld_l2x4(hA[q], sp + (size_t)q * 32);
        asm volatile("s_waitcnt vmcnt(8)");
        __builtin_amdgcn_sched_barrier(0xF4);
        #pragma unroll
        for (int q = 0; q < 8; ++q) {
          #pragma unroll
          for (int ji = 0; ji < 8; ++ji)
            acc[ji] += w4[ji * 256 + kb + q] * hA[q];
        }
        asm volatile("s_waitcnt vmcnt(0)");
        __builtin_amdgcn_sched_barrier(0xF4);
        #pragma unroll
        for (int q = 8; q < 16; ++q) {
          #pragma unroll
          for (int ji = 0; ji < 8; ++ji)
            acc[ji] += w4[ji * 256 + kb + q] * hA[q];
        }
      } else {
        // layer 1: mh=0 -> y0 . Wih1 ; mh=1 -> h1 . Whh1 (full K each)
        const float* hb = (mh == 0) ? (rp ? ws + H01 : ws + H00)
                                    : (rp ? ws + H11 : ws + H10);
        const int kq0 = ks * 32;
        const f4* sp = (const f4*)hb + b + (size_t)kq0 * 32;
        f4 hA[16], hB[16];
        #pragma unroll
        for (int q = 0; q < 16; ++q) ld_l2x4(hA[q], sp + (size_t)q * 32);
        #pragma unroll
        for (int q = 0; q < 16; ++q) ld_l2x4(hB[q], sp + (size_t)(q + 16) * 32);
        asm volatile("s_waitcnt vmcnt(16)");
        __builtin_amdgcn_sched_barrier(0xF4);
        #pragma unroll
        for (int q = 0; q < 16; ++q) {
          #pragma unroll
          for (int ji = 0; ji < 8; ++ji)
            acc[ji] += w4[mh * 2048 + ji * 256 + kq0 + q] * hA[q];
        }
        asm volatile("s_waitcnt vmcnt(0)");
        __builtin_amdgcn_sched_barrier(0xF4);
        #pragma unroll
        for (int q = 0; q < 16; ++q) {
          #pragma unroll
          for (int ji = 0; ji < 8; ++ji)
            acc[ji] += w4[mh * 2048 + ji * 256 + kq0 + 16 + q] * hB[q];
        }
      }
      const int slot = mh * 8 + ks;
      #pragma unroll
      for (int ji = 0; ji < 8; ++ji)
        part[(slot * 8 + ji) * 32 + b] =
            (acc[ji][0] + acc[ji][1]) + (acc[ji][2] + acc[ji][3]);
    }
    __syncthreads();

    if (active && tid < 256) {
      float sum = bias + pv;
      #pragma unroll
      for (int r = 0; r < 16; ++r) sum += part[(r * 8 + rj) * 32 + b];
      float hv = tanhf(sum);
      float* dst = isL1 ? (rp ? ws + H10 : ws + H11)
                        : (rp ? ws + H00 : ws + H01);
      st_cohf(dst + ((jout >> 2) * 128 + b * 4 + (jout & 3)), hv);
      if (isL1) {
        lg0 = fmaf(hv, Wcls[(size_t)(s - 1) * 1024 + jout], lg0);
        lg1 = fmaf(hv, Wcls[(size_t)524288 + (size_t)(s - 1) * 1024 + jout], lg1);
        if (s == 512) out[64 + 32768 + (size_t)b * 1024 + jout] = hv;
      } else if (s == 511) {
        out[64 + (size_t)b * 1024 + jout] = hv;
      }
    }
    __syncthreads();  // drains h stores (vmcnt 0) before flag publish
    if (tid == 0) st_cohu(&flags[myflag], (unsigned)(s + 1));
  }

  // ---- epilogue: classifier ----
  if (isL1) {
    if (tid < 256) { part[tid] = lg0; part[256 + tid] = lg1; }
    __syncthreads();
    if (tid < 64) {
      const int c = tid >> 5, bb = tid & 31;
      float v = 0.f;
      #pragma unroll
      for (int ji = 0; ji < 8; ++ji) v += part[c * 256 + ji * 32 + bb];
      st_cohf(&ws[PLOG + (size_t)(bid - 128) * 64 + c * 32 + bb], v);
    }
    __syncthreads();  // drain plog stores
    if (tid == 0) st_cohu(&flags[128 + (bid - 128)], 600u);
  } else if (bid == 0) {
    if (tid < 128) {
      const unsigned* fp = flags + 128 + tid;
      while (!__all(ld_flag(fp) >= 600u)) {}
    }
    __syncthreads();
    __builtin_amdgcn_sched_barrier(0);
    const int pair = tid & 63, bg = tid >> 6;  // bg 0..7
    float v = 0.f;
    #pragma unroll 4
    for (int blk = bg; blk < 128; blk += 8)
      v += ws[PLOG + (size_t)blk * 64 + pair];
    part[tid] = v;
    __syncthreads();
    if (tid < 64) {
      float s2 = bcls[tid >> 5];
      #pragma unroll
      for (int g2 = 0; g2 < 8; ++g2) s2 += part[g2 * 64 + tid];
      out[(size_t)(tid & 31) * 2 + (tid >> 5)] = s2;  // logits [B,C]
    }
  }
}

extern "C" void kernel_launch(void* const* d_in, const int* in_sizes, int n_in,
                              void* d_out, int out_size, void* d_ws, size_t ws_size,
                              hipStream_t stream) {
  const float* x    = (const float*)d_in[0];
  const float* h0   = (const float*)d_in[1];
  const float* Wih0 = (const float*)d_in[2];
  const float* Whh0 = (const float*)d_in[3];
  const float* bih0 = (const float*)d_in[4];
  const float* bhh0 = (const float*)d_in[5];
  const float* Wih1 = (const float*)d_in[6];
  const float* Whh1 = (const float*)d_in[7];
  const float* bih1 = (const float*)d_in[8];
  const float* bhh1 = (const float*)d_in[9];
  const float* Wcls = (const float*)d_in[10];
  const float* bcls = (const float*)d_in[11];
  float* out = (float*)d_out;
  float* ws  = (float*)d_ws;

  hipFuncSetAttribute((const void*)rnn_kernel,
                      hipFuncAttributeMaxDynamicSharedMemorySize, 81920);

  hipLaunchKernelGGL(init_kernel, dim3(256), dim3(256), 0, stream, h0, ws);
  hipLaunchKernelGGL(pre_kernel, dim3(8192), dim3(256), 0, stream, x, Wih0, ws);

  void* args[] = { (void*)&Whh0, (void*)&bih0, (void*)&bhh0,
                   (void*)&Wih1, (void*)&Whh1, (void*)&bih1, (void*)&bhh1,
                   (void*)&Wcls, (void*)&bcls, (void*)&out, (void*)&ws };
  hipLaunchCooperativeKernel((void*)rnn_kernel, dim3(256), dim3(512), args,
                             81920, stream);
}

// Round 5
// 5881.438 us; speedup vs baseline: 2.5883x; 1.3417x over previous
//
#include <hip/hip_runtime.h>
#include <math.h>

typedef float f4 __attribute__((ext_vector_type(4)));

#define NT 512

// ws float offsets
#define H00 0
#define H01 32768
#define H10 65536
#define H11 98304
#define PLOG 131072      // 256*64 floats
#define FLAGS 147456     // 8192 uints (256 flags @ stride 32) + rel at uint 8192
#define PRE 156160       // 512*32768 floats = 64 MB

__device__ __forceinline__ void ld_l2x4(f4& d, const f4* p) {
  // L1-bypassing (coherent) load, L2 allowed; completion via counted vmcnt
  asm volatile("global_load_dwordx4 %0, %1, off sc0" : "=v"(d) : "v"(p));
}
__device__ __forceinline__ void st_cohf(float* p, float v) {
  __hip_atomic_store(p, v, __ATOMIC_RELAXED, __HIP_MEMORY_SCOPE_AGENT);
}
__device__ __forceinline__ void st_cohu(unsigned* p, unsigned v) {
  __hip_atomic_store(p, v, __ATOMIC_RELAXED, __HIP_MEMORY_SCOPE_AGENT);
}
__device__ __forceinline__ unsigned ld_flag(const unsigned* p) {
  return __hip_atomic_load(p, __ATOMIC_RELAXED, __HIP_MEMORY_SCOPE_AGENT);
}

__global__ __launch_bounds__(256) void init_kernel(const float* __restrict__ h0,
                                                   float* __restrict__ ws) {
  int g = blockIdx.x * 256 + threadIdx.x;  // 0..65535 == l*32768 + b*1024 + k
  int l = g >> 15;
  int b = (g >> 10) & 31;
  int k = g & 1023;
  size_t base = l ? (size_t)H11 : (size_t)H00;
  ws[base + (size_t)(k >> 2) * 128 + b * 4 + (k & 3)] = h0[g];
  if (g < 8704) ((unsigned*)(ws + FLAGS))[g] = 0u;
}

// pre[t,j,b] = sum_k x[b,t,k]*Wih0[j,k]; one block per t, x[:,t,:] staged in LDS.
__global__ __launch_bounds__(512) void pre_kernel(const float* __restrict__ x,
                                                  const float* __restrict__ W,
                                                  float* __restrict__ ws) {
  extern __shared__ float xs[];        // 32768 floats = 128 KB: xl[k4 256][b 32]
  f4* xl = (f4*)xs;
  const int t = blockIdx.x;
  const int tid = threadIdx.x;
  const int b = tid & 31, jg = tid >> 5;   // jg 0..15
  {
    const int kk = tid >> 5;               // 0..15 -> k4 range kk*16..+15
    const f4* xp = (const f4*)x + ((size_t)b * NT + t) * 256 + kk * 16;
    #pragma unroll
    for (int q = 0; q < 16; ++q) xl[(kk * 16 + q) * 32 + b] = xp[q];
  }
  __syncthreads();
  f4* pre4 = (f4*)(ws + PRE) + (size_t)t * 8192;
  for (int jt = 0; jt < 4; ++jt) {
    f4 acc[16];
    #pragma unroll
    for (int i = 0; i < 16; ++i) acc[i] = (f4)0.f;
    const f4* wrow = (const f4*)W + (size_t)(jg * 64 + jt * 16) * 256;
    for (int k4 = 0; k4 < 256; ++k4) {
      f4 xv = xl[k4 * 32 + b];
      #pragma unroll
      for (int ji = 0; ji < 16; ++ji)
        acc[ji] += wrow[(size_t)ji * 256 + k4] * xv;
    }
    #pragma unroll
    for (int g4 = 0; g4 < 4; ++g4) {
      f4 o;
      #pragma unroll
      for (int e = 0; e < 4; ++e) {
        f4 a = acc[g4 * 4 + e];
        o[e] = (a[0] + a[1]) + (a[2] + a[3]);
      }
      pre4[(size_t)(jg * 16 + jt * 4 + g4) * 32 + b] = o;
    }
  }
}

// Persistent kernel: 256 balanced blocks, each owns rows bid*4..+3 of
// Whh0 (->h0), Wih1 and Whh1 (->h1). Relay barrier via block 0.
__global__ __launch_bounds__(512, 1) void rnn_kernel(
    const float* __restrict__ bih0, const float* __restrict__ bhh0,
    const float* __restrict__ Whh0, const float* __restrict__ Wih1,
    const float* __restrict__ Whh1,
    const float* __restrict__ bih1, const float* __restrict__ bhh1,
    const float* __restrict__ Wcls, const float* __restrict__ bcls,
    float* __restrict__ out, float* ws) {
  extern __shared__ float smem[];
  f4* w4 = (f4*)smem;                  // 3072 f4 = 48 KB: [mat 3][row 4][k4 256]
  float* part = smem + 12288;          // 6144 floats: [kg 16][row 12][b 32]

  const int bid = blockIdx.x, tid = threadIdx.x;
  const int b = tid & 31, kg = tid >> 5;     // kg 0..15
  const int kq0 = kg * 16;                   // f4 k-base

  unsigned* flags = (unsigned*)(ws + FLAGS);
  unsigned* rel = flags + 8192;

  // stage 12 weight rows
  {
    const f4* s0 = (const f4*)Whh0 + (size_t)(bid * 4) * 256;
    const f4* s1 = (const f4*)Wih1 + (size_t)(bid * 4) * 256;
    const f4* s2 = (const f4*)Whh1 + (size_t)(bid * 4) * 256;
    for (int i = tid; i < 1024; i += 512) {
      w4[i] = s0[i]; w4[1024 + i] = s1[i]; w4[2048 + i] = s2[i];
    }
  }

  // reducer constants (tid<256): rj 0..7; rj<4 -> h0 col j, rj>=4 -> h1 col j1
  const int rj = tid >> 5;
  const int jcol = bid * 4 + (rj & 3);
  float bias = 0.f;
  if (tid < 256)
    bias = (rj < 4) ? (bih0[jcol] + bhh0[jcol]) : (bih1[jcol] + bhh1[jcol]);

  float lg0 = 0.f, lg1 = 0.f;
  __syncthreads();

  for (int s = 0; s <= NT; ++s) {
    // ---- barrier: wait for epoch s ----
    if (bid == 0) {
      if (tid < 256) {
        const unsigned* fp = &flags[tid * 32];
        while (ld_flag(fp) < (unsigned)s) {}
      }
      __syncthreads();
      if (tid == 0) st_cohu(rel, (unsigned)s);
    } else {
      while (ld_flag(rel) < (unsigned)s) {}
    }
    __builtin_amdgcn_sched_barrier(0);

    const int rp = s & 1;
    const bool l0 = (s < NT), l1 = (s >= 1);

    // prefetches (older than the counted h-load batch -> counting stays safe)
    float pv = 0.f, wc0 = 0.f, wc1 = 0.f;
    if (tid < 256) {
      if (rj < 4) {
        if (l0) pv = ws[PRE + (size_t)s * 32768 + bid * 128 + b * 4 + rj];
      } else {
        const int t = (s >= 1) ? s - 1 : 0;
        wc0 = Wcls[(size_t)t * 1024 + jcol];
        wc1 = Wcls[(size_t)524288 + (size_t)t * 1024 + jcol];
      }
    }

    // ---- batched coherent h loads (32 in flight) ----
    const f4* pa = (const f4*)(ws + (rp ? H01 : H00)) + b;
    const f4* pb = (const f4*)(ws + (rp ? H11 : H10)) + b;
    f4 hA[16], hB[16];
    #pragma unroll
    for (int q = 0; q < 16; ++q) ld_l2x4(hA[q], pa + (size_t)(kq0 + q) * 32);
    #pragma unroll
    for (int q = 0; q < 16; ++q) ld_l2x4(hB[q], pb + (size_t)(kq0 + q) * 32);

    f4 acc[12];
    #pragma unroll
    for (int r = 0; r < 12; ++r) acc[r] = (f4)0.f;

    asm volatile("s_waitcnt vmcnt(24)");      // hA[0..7] done
    __builtin_amdgcn_sched_barrier(0xF4);
    #pragma unroll
    for (int q = 0; q < 8; ++q) {
      #pragma unroll
      for (int r = 0; r < 8; ++r)
        acc[r] += w4[r * 256 + kq0 + q] * hA[q];
    }
    asm volatile("s_waitcnt vmcnt(16)");      // hA[8..15] done
    __builtin_amdgcn_sched_barrier(0xF4);
    #pragma unroll
    for (int q = 8; q < 16; ++q) {
      #pragma unroll
      for (int r = 0; r < 8; ++r)
        acc[r] += w4[r * 256 + kq0 + q] * hA[q];
    }
    asm volatile("s_waitcnt vmcnt(0)");       // hB done
    __builtin_amdgcn_sched_barrier(0xF4);
    #pragma unroll
    for (int q = 0; q < 16; ++q) {
      #pragma unroll
      for (int r = 0; r < 4; ++r)
        acc[8 + r] += w4[2048 + r * 256 + kq0 + q] * hB[q];
    }

    #pragma unroll
    for (int r = 0; r < 12; ++r)
      part[(kg * 12 + r) * 32 + b] =
          (acc[r][0] + acc[r][1]) + (acc[r][2] + acc[r][3]);
    __syncthreads();

    // ---- reduce + tanh + state store ----
    if (tid < 256) {
      if (rj < 4) {
        if (l0) {
          float sum = bias + pv;
          #pragma unroll
          for (int k = 0; k < 16; ++k) sum += part[(k * 12 + rj) * 32 + b];
          float hv = tanhf(sum);
          float* dst = ws + (rp ? H00 : H01);
          st_cohf(dst + (bid * 128 + b * 4 + rj), hv);
          if (s == NT - 1) out[64 + (size_t)b * 1024 + jcol] = hv;
        }
      } else {
        if (l1) {
          const int r1 = rj - 4;
          float sum = bias;
          #pragma unroll
          for (int k = 0; k < 16; ++k)
            sum += part[(k * 12 + 4 + r1) * 32 + b] +
                   part[(k * 12 + 8 + r1) * 32 + b];
          float hv = tanhf(sum);
          float* dst = ws + (rp ? H10 : H11);
          st_cohf(dst + (bid * 128 + b * 4 + r1), hv);
          lg0 = fmaf(hv, wc0, lg0);
          lg1 = fmaf(hv, wc1, lg1);
          if (s == NT) out[64 + 32768 + (size_t)b * 1024 + jcol] = hv;
        }
      }
    }
    __syncthreads();  // drains all stores (vmcnt 0) before flag publish
    if (tid == 0) st_cohu(&flags[bid * 32], (unsigned)(s + 1));
  }

  // ---- epilogue: classifier ----
  if (tid < 256 && rj >= 4) {
    const int r1 = rj - 4;
    part[r1 * 64 + b] = lg0;
    part[r1 * 64 + 32 + b] = lg1;
  }
  __syncthreads();
  if (tid < 64) {
    const int c = tid >> 5, bb = tid & 31;
    float v = 0.f;
    #pragma unroll
    for (int r1 = 0; r1 < 4; ++r1) v += part[r1 * 64 + c * 32 + bb];
    st_cohf(&ws[PLOG + (size_t)bid * 64 + c * 32 + bb], v);
  }
  __syncthreads();  // drain plog stores
  if (tid == 0) st_cohu(&flags[bid * 32], 600u);

  if (bid == 0) {
    if (tid < 256) {
      const unsigned* fp = &flags[tid * 32];
      while (ld_flag(fp) < 600u) {}
    }
    __syncthreads();
    __builtin_amdgcn_sched_barrier(0);
    if (tid < 256) {
      const int g = tid >> 6, pair = tid & 63;  // g 0..3
      float v = 0.f;
      for (int blk = g; blk < 256; blk += 4)
        v += __hip_atomic_load(&ws[PLOG + (size_t)blk * 64 + pair],
                               __ATOMIC_RELAXED, __HIP_MEMORY_SCOPE_AGENT);
      part[tid] = v;
    }
    __syncthreads();
    if (tid < 64) {
      float s2 = bcls[tid >> 5];
      #pragma unroll
      for (int g = 0; g < 4; ++g) s2 += part[g * 64 + tid];
      out[(size_t)(tid & 31) * 2 + (tid >> 5)] = s2;  // logits [B,C]
    }
  }
}

extern "C" void kernel_launch(void* const* d_in, const int* in_sizes, int n_in,
                              void* d_out, int out_size, void* d_ws, size_t ws_size,
                              hipStream_t stream) {
  const float* x    = (const float*)d_in[0];
  const float* h0   = (const float*)d_in[1];
  const float* Wih0 = (const float*)d_in[2];
  const float* Whh0 = (const float*)d_in[3];
  const float* bih0 = (const float*)d_in[4];
  const float* bhh0 = (const float*)d_in[5];
  const float* Wih1 = (const float*)d_in[6];
  const float* Whh1 = (const float*)d_in[7];
  const float* bih1 = (const float*)d_in[8];
  const float* bhh1 = (const float*)d_in[9];
  const float* Wcls = (const float*)d_in[10];
  const float* bcls = (const float*)d_in[11];
  float* out = (float*)d_out;
  float* ws  = (float*)d_ws;

  hipFuncSetAttribute((const void*)pre_kernel,
                      hipFuncAttributeMaxDynamicSharedMemorySize, 131072);
  hipFuncSetAttribute((const void*)rnn_kernel,
                      hipFuncAttributeMaxDynamicSharedMemorySize, 73728);

  hipLaunchKernelGGL(init_kernel, dim3(256), dim3(256), 0, stream, h0, ws);
  hipLaunchKernelGGL(pre_kernel, dim3(512), dim3(512), 131072, stream, x, Wih0, ws);

  void* args[] = { (void*)&bih0, (void*)&bhh0, (void*)&Whh0, (void*)&Wih1,
                   (void*)&Whh1, (void*)&bih1, (void*)&bhh1,
                   (void*)&Wcls, (void*)&bcls, (void*)&out, (void*)&ws };
  hipLaunchCooperativeKernel((void*)rnn_kernel, dim3(256), dim3(512), args,
                             73728, stream);
}

// Round 6
// 4912.456 us; speedup vs baseline: 3.0988x; 1.1972x over previous
//
#include <hip/hip_runtime.h>
#include <math.h>

typedef float f4 __attribute__((ext_vector_type(4)));

#define NT 512

// ws float offsets
#define H00 0
#define H01 32768
#define H10 65536
#define H11 98304
#define PLOG 131072      // 256*64 floats
#define FLAGS 147456     // uints: flags[bid*32] (0..8191), rel @8192, relx[g] @8256+g*32

__device__ __forceinline__ void ld_l2x4(f4& d, const f4* p) {
  // L1-bypassing coherent load (L2 allowed); completion via counted vmcnt
  asm volatile("global_load_dwordx4 %0, %1, off sc0" : "=v"(d) : "v"(p));
}
__device__ __forceinline__ void ld_x4(f4& d, const f4* p) {
  // plain load (read-only x), manually counted
  asm volatile("global_load_dwordx4 %0, %1, off" : "=v"(d) : "v"(p));
}
__device__ __forceinline__ void st_cohf(float* p, float v) {
  __hip_atomic_store(p, v, __ATOMIC_RELAXED, __HIP_MEMORY_SCOPE_AGENT);
}
__device__ __forceinline__ void st_cohu(unsigned* p, unsigned v) {
  __hip_atomic_store(p, v, __ATOMIC_RELAXED, __HIP_MEMORY_SCOPE_AGENT);
}
__device__ __forceinline__ unsigned ld_flag(const unsigned* p) {
  return __hip_atomic_load(p, __ATOMIC_RELAXED, __HIP_MEMORY_SCOPE_AGENT);
}
__device__ __forceinline__ float hsum(f4 a) {
  return (a[0] + a[1]) + (a[2] + a[3]);
}

__global__ __launch_bounds__(256) void init_kernel(const float* __restrict__ h0,
                                                   float* __restrict__ ws) {
  int g = blockIdx.x * 256 + threadIdx.x;  // 0..65535 == l*32768 + b*1024 + k
  int l = g >> 15;
  int b = (g >> 10) & 31;
  int k = g & 1023;
  size_t base = l ? (size_t)H11 : (size_t)H00;
  ws[base + (size_t)(k >> 2) * 128 + b * 4 + (k & 3)] = h0[g];
  if (g < 8704) ((unsigned*)(ws + FLAGS))[g] = 0u;
}

// Persistent kernel: 256 blocks, block bid owns rows bid*4..+3 of
// Whh0, Wih1, Whh1 AND Wih0 (input projection folded into barrier slack).
__global__ __launch_bounds__(512, 1) void rnn_kernel(
    const float* __restrict__ x,
    const float* __restrict__ bih0, const float* __restrict__ bhh0,
    const float* __restrict__ Whh0, const float* __restrict__ Wih0,
    const float* __restrict__ Wih1, const float* __restrict__ Whh1,
    const float* __restrict__ bih1, const float* __restrict__ bhh1,
    const float* __restrict__ Wcls, const float* __restrict__ bcls,
    float* __restrict__ out, float* ws) {
  extern __shared__ float smem[];
  f4* w4 = (f4*)smem;                    // 4096 f4 = 64 KB: [Whh0|Wih1|Whh1|Wih0] x 4 rows x 256 f4
  float* part = smem + 16384;            // 6144 floats: [kg 16][row 12][b 32]
  float* prebuf = smem + 22528;          // 2048 floats: [kg 16][r 4][b 32]

  const int bid = blockIdx.x, tid = threadIdx.x;
  const int b = tid & 31, kg = tid >> 5;     // kg 0..15
  const int kq0 = kg * 16;                   // f4 k-base (covers 64 k)

  unsigned* flags = (unsigned*)(ws + FLAGS);
  unsigned* rel = flags + 8192;
  unsigned* relx = flags + 8256;

  // stage 16 weight rows (4 per matrix)
  {
    const f4* s0 = (const f4*)Whh0 + (size_t)(bid * 4) * 256;
    const f4* s1 = (const f4*)Wih1 + (size_t)(bid * 4) * 256;
    const f4* s2 = (const f4*)Whh1 + (size_t)(bid * 4) * 256;
    const f4* s3 = (const f4*)Wih0 + (size_t)(bid * 4) * 256;
    for (int i = tid; i < 1024; i += 512) {
      w4[i] = s0[i]; w4[1024 + i] = s1[i];
      w4[2048 + i] = s2[i]; w4[3072 + i] = s3[i];
    }
  }

  // reducer constants (tid<256): rj 0..7; rj<4 -> h0 col, rj>=4 -> h1 col
  const int rj = tid >> 5;
  const int jcol = bid * 4 + (rj & 3);
  float bias = 0.f;
  if (tid < 256)
    bias = (rj < 4) ? (bih0[jcol] + bhh0[jcol]) : (bih1[jcol] + bhh1[jcol]);

  float lg0 = 0.f, lg1 = 0.f;
  __syncthreads();  // weights staged

  // ---- prologue: prebuf for t=0 ----
  {
    const f4* xq = (const f4*)x + ((size_t)b * NT + 0) * 256 + kq0;
    f4 xp[16];
    #pragma unroll
    for (int q = 0; q < 16; ++q) ld_x4(xp[q], xq + q);
    asm volatile("s_waitcnt vmcnt(0)");
    __builtin_amdgcn_sched_barrier(0xF4);
    f4 p0 = (f4)0.f, p1 = (f4)0.f, p2 = (f4)0.f, p3 = (f4)0.f;
    #pragma unroll
    for (int q = 0; q < 16; ++q) {
      p0 += w4[3072 + 0 * 256 + kq0 + q] * xp[q];
      p1 += w4[3072 + 1 * 256 + kq0 + q] * xp[q];
      p2 += w4[3072 + 2 * 256 + kq0 + q] * xp[q];
      p3 += w4[3072 + 3 * 256 + kq0 + q] * xp[q];
    }
    prebuf[(kg * 4 + 0) * 32 + b] = hsum(p0);
    prebuf[(kg * 4 + 1) * 32 + b] = hsum(p1);
    prebuf[(kg * 4 + 2) * 32 + b] = hsum(p2);
    prebuf[(kg * 4 + 3) * 32 + b] = hsum(p3);
  }

  for (int s = 0; s <= NT; ++s) {
    // ---- grid barrier for epoch s: 1 spinner/block + relay ----
    if (bid == 0) {
      if (tid > 0 && tid < 256) {
        const unsigned* fp = &flags[tid * 32];
        while (ld_flag(fp) < (unsigned)s) {}
      }
      __syncthreads();
      if (tid == 0) { st_cohu(rel, (unsigned)s); st_cohu(relx, (unsigned)s); }
    } else if (bid < 8) {
      if (tid == 0) {
        while (ld_flag(rel) < (unsigned)s) {}
        st_cohu(&relx[bid * 32], (unsigned)s);
      }
      __syncthreads();
    } else {
      if (tid == 0) {
        const unsigned* rxp = &relx[(bid & 7) * 32];
        while (ld_flag(rxp) < (unsigned)s) {}
      }
      __syncthreads();
    }
    __builtin_amdgcn_sched_barrier(0);

    const int rp = s & 1;
    const bool l1act = (s >= 1);

    // Wcls prefetch (pinned OLDER than the counted h-load batch)
    float wc0 = 0.f, wc1 = 0.f;
    if (tid < 256 && rj >= 4) {
      const int t = l1act ? (s - 1) : 0;
      wc0 = Wcls[(size_t)t * 1024 + jcol];
      wc1 = Wcls[(size_t)524288 + (size_t)t * 1024 + jcol];
    }
    __builtin_amdgcn_sched_barrier(0);

    // ---- batched coherent h loads (32 in flight) ----
    const f4* pa = (const f4*)(ws + (rp ? H01 : H00)) + b;
    const f4* pb = (const f4*)(ws + (rp ? H11 : H10)) + b;
    f4 hA[16], hB[16], xv[16];
    #pragma unroll
    for (int q = 0; q < 16; ++q) ld_l2x4(hA[q], pa + (size_t)(kq0 + q) * 32);
    #pragma unroll
    for (int q = 0; q < 16; ++q) ld_l2x4(hB[q], pb + (size_t)(kq0 + q) * 32);

    f4 acc[12];
    #pragma unroll
    for (int r = 0; r < 12; ++r) acc[r] = (f4)0.f;

    asm volatile("s_waitcnt vmcnt(24)");      // hA[0..7] done
    __builtin_amdgcn_sched_barrier(0xF4);
    #pragma unroll
    for (int q = 0; q < 8; ++q) {
      #pragma unroll
      for (int r = 0; r < 8; ++r)
        acc[r] += w4[r * 256 + kq0 + q] * hA[q];
    }
    asm volatile("s_waitcnt vmcnt(16)");      // hA[8..15] done
    __builtin_amdgcn_sched_barrier(0xF4);
    #pragma unroll
    for (int q = 8; q < 16; ++q) {
      #pragma unroll
      for (int r = 0; r < 8; ++r)
        acc[r] += w4[r * 256 + kq0 + q] * hA[q];
    }

    // issue next-step x loads (newest 16; HBM latency hides under FMA-B+reduce)
    const int tn = (s + 1 < NT) ? (s + 1) : (NT - 1);
    {
      const f4* xq = (const f4*)x + ((size_t)b * NT + tn) * 256 + kq0;
      #pragma unroll
      for (int q = 0; q < 16; ++q) ld_x4(xv[q], xq + q);
    }

    asm volatile("s_waitcnt vmcnt(16)");      // hB done (x are the 16 newest)
    __builtin_amdgcn_sched_barrier(0xF4);
    #pragma unroll
    for (int q = 0; q < 16; ++q) {
      #pragma unroll
      for (int r = 0; r < 4; ++r)
        acc[8 + r] += w4[2048 + r * 256 + kq0 + q] * hB[q];
    }

    #pragma unroll
    for (int r = 0; r < 12; ++r)
      part[(kg * 12 + r) * 32 + b] = hsum(acc[r]);
    __syncthreads();   // also drains xv loads (vmcnt 0 at barrier)

    // ---- reduce + tanh + state store ----
    if (tid < 256) {
      if (rj < 4) {
        if (s < NT) {
          float sum = bias;
          #pragma unroll
          for (int k = 0; k < 16; ++k) sum += part[(k * 12 + rj) * 32 + b];
          #pragma unroll
          for (int k = 0; k < 16; ++k) sum += prebuf[(k * 4 + rj) * 32 + b];
          float hv = tanhf(sum);
          float* dst = ws + (rp ? H00 : H01);
          st_cohf(dst + (bid * 128 + b * 4 + rj), hv);
          if (s == NT - 1) out[64 + (size_t)b * 1024 + jcol] = hv;
        }
      } else if (l1act) {
        const int r1 = rj - 4;
        float sum = bias;
        #pragma unroll
        for (int k = 0; k < 16; ++k)
          sum += part[(k * 12 + 4 + r1) * 32 + b] +
                 part[(k * 12 + 8 + r1) * 32 + b];
        float hv = tanhf(sum);
        float* dst = ws + (rp ? H10 : H11);
        st_cohf(dst + (bid * 128 + b * 4 + r1), hv);
        lg0 = fmaf(hv, wc0, lg0);
        lg1 = fmaf(hv, wc1, lg1);
        if (s == NT) out[64 + 32768 + (size_t)b * 1024 + jcol] = hv;
      }
    }
    __syncthreads();  // drains h stores before flag publish
    if (tid == 0) st_cohu(&flags[bid * 32], (unsigned)(s + 1));

    // ---- input-projection partials for t=tn (barrier slack) ----
    {
      f4 p0 = (f4)0.f, p1 = (f4)0.f, p2 = (f4)0.f, p3 = (f4)0.f;
      #pragma unroll
      for (int q = 0; q < 16; ++q) {
        p0 += w4[3072 + 0 * 256 + kq0 + q] * xv[q];
        p1 += w4[3072 + 1 * 256 + kq0 + q] * xv[q];
        p2 += w4[3072 + 2 * 256 + kq0 + q] * xv[q];
        p3 += w4[3072 + 3 * 256 + kq0 + q] * xv[q];
      }
      prebuf[(kg * 4 + 0) * 32 + b] = hsum(p0);
      prebuf[(kg * 4 + 1) * 32 + b] = hsum(p1);
      prebuf[(kg * 4 + 2) * 32 + b] = hsum(p2);
      prebuf[(kg * 4 + 3) * 32 + b] = hsum(p3);
    }
  }

  // ---- epilogue: classifier ----
  if (tid < 256 && rj >= 4) {
    const int r1 = rj - 4;
    part[r1 * 64 + b] = lg0;
    part[r1 * 64 + 32 + b] = lg1;
  }
  __syncthreads();
  if (tid < 64) {
    const int c = tid >> 5, bb = tid & 31;
    float v = 0.f;
    #pragma unroll
    for (int r1 = 0; r1 < 4; ++r1) v += part[r1 * 64 + c * 32 + bb];
    st_cohf(&ws[PLOG + (size_t)bid * 64 + c * 32 + bb], v);
  }
  __syncthreads();  // drain plog stores
  if (tid == 0) st_cohu(&flags[bid * 32], 600u);

  if (bid == 0) {
    if (tid > 0 && tid < 256) {
      const unsigned* fp = &flags[tid * 32];
      while (ld_flag(fp) < 600u) {}
    }
    __syncthreads();
    __builtin_amdgcn_sched_barrier(0);
    if (tid < 256) {
      const int g = tid >> 6, pair = tid & 63;  // g 0..3
      float v = 0.f;
      for (int blk = g; blk < 256; blk += 4)
        v += __hip_atomic_load(&ws[PLOG + (size_t)blk * 64 + pair],
                               __ATOMIC_RELAXED, __HIP_MEMORY_SCOPE_AGENT);
      part[tid] = v;
    }
    __syncthreads();
    if (tid < 64) {
      float s2 = bcls[tid >> 5];
      #pragma unroll
      for (int g = 0; g < 4; ++g) s2 += part[g * 64 + tid];
      out[(size_t)(tid & 31) * 2 + (tid >> 5)] = s2;  // logits [B,C]
    }
  }
}

extern "C" void kernel_launch(void* const* d_in, const int* in_sizes, int n_in,
                              void* d_out, int out_size, void* d_ws, size_t ws_size,
                              hipStream_t stream) {
  const float* x    = (const float*)d_in[0];
  const float* h0   = (const float*)d_in[1];
  const float* Wih0 = (const float*)d_in[2];
  const float* Whh0 = (const float*)d_in[3];
  const float* bih0 = (const float*)d_in[4];
  const float* bhh0 = (const float*)d_in[5];
  const float* Wih1 = (const float*)d_in[6];
  const float* Whh1 = (const float*)d_in[7];
  const float* bih1 = (const float*)d_in[8];
  const float* bhh1 = (const float*)d_in[9];
  const float* Wcls = (const float*)d_in[10];
  const float* bcls = (const float*)d_in[11];
  float* out = (float*)d_out;
  float* ws  = (float*)d_ws;

  hipFuncSetAttribute((const void*)rnn_kernel,
                      hipFuncAttributeMaxDynamicSharedMemorySize, 98304);

  hipLaunchKernelGGL(init_kernel, dim3(256), dim3(256), 0, stream, h0, ws);

  void* args[] = { (void*)&x, (void*)&bih0, (void*)&bhh0, (void*)&Whh0,
                   (void*)&Wih0, (void*)&Wih1, (void*)&Whh1,
                   (void*)&bih1, (void*)&bhh1,
                   (void*)&Wcls, (void*)&bcls, (void*)&out, (void*)&ws };
  hipLaunchCooperativeKernel((void*)rnn_kernel, dim3(256), dim3(512), args,
                             98304, stream);
}

// Round 7
// 3767.375 us; speedup vs baseline: 4.0407x; 1.3039x over previous
//
#include <hip/hip_runtime.h>
#include <math.h>

typedef float f4 __attribute__((ext_vector_type(4)));

#define NT 512

// ws float offsets
#define H00 0
#define H01 32768
#define H10 65536
#define H11 98304
#define PLOG 131072      // 256*64 floats
#define FLAGS 147456     // uints: flags[bid] @ bid*32 (0..8191); relc[g] @ 8192+g*32
#define X4 156160        // 512*256*32 f4 = 64 MB, layout [t][k4][b]

__device__ __forceinline__ void ld_l2x4(f4& d, const f4* p) {
  // L1-bypassing coherent load (MALL-coherent, R2/R4/R5-validated); counted vmcnt
  asm volatile("global_load_dwordx4 %0, %1, off sc0" : "=v"(d) : "v"(p));
}
__device__ __forceinline__ void ld_x4(f4& d, const f4* p) {
  asm volatile("global_load_dwordx4 %0, %1, off" : "=v"(d) : "v"(p));
}
__device__ __forceinline__ void st_cohf(float* p, float v) {
  __hip_atomic_store(p, v, __ATOMIC_RELAXED, __HIP_MEMORY_SCOPE_AGENT);
}
__device__ __forceinline__ void st_cohu(unsigned* p, unsigned v) {
  __hip_atomic_store(p, v, __ATOMIC_RELAXED, __HIP_MEMORY_SCOPE_AGENT);
}
__device__ __forceinline__ unsigned ld_flag(const unsigned* p) {
  return __hip_atomic_load(p, __ATOMIC_RELAXED, __HIP_MEMORY_SCOPE_AGENT);
}
__device__ __forceinline__ float hsum(f4 a) {
  return (a[0] + a[1]) + (a[2] + a[3]);
}

__global__ __launch_bounds__(256) void init_kernel(const float* __restrict__ h0,
                                                   float* __restrict__ ws) {
  int g = blockIdx.x * 256 + threadIdx.x;  // 0..65535 == l*32768 + b*1024 + k
  int l = g >> 15;
  int b = (g >> 10) & 31;
  int k = g & 1023;
  size_t base = l ? (size_t)H11 : (size_t)H00;
  ws[base + (size_t)(k >> 2) * 128 + b * 4 + (k & 3)] = h0[g];
  if (g < 8704) ((unsigned*)(ws + FLAGS))[g] = 0u;
}

// x[b][t][k] -> x4[t][k4][b]  (coalesced writes; one-time)
__global__ __launch_bounds__(256) void xpose_kernel(const float* __restrict__ x,
                                                    float* __restrict__ ws) {
  f4* x4 = (f4*)(ws + X4);
  const f4* xs = (const f4*)x;
  const int t = blockIdx.x;
  const int kqq = threadIdx.x >> 5;   // 0..7
  const int b = threadIdx.x & 31;
  #pragma unroll 4
  for (int i = 0; i < 32; ++i) {
    const int kq = kqq * 32 + i;      // 0..255
    f4 v = xs[((size_t)b * NT + t) * 256 + kq];
    x4[((size_t)t * 256 + kq) * 32 + b] = v;
  }
}

// Persistent kernel: 256 blocks; block bid owns rows bid*4..+3 of
// Whh0, Wih1, Whh1, Wih0 (input projection folded into barrier slack).
__global__ __launch_bounds__(512, 1) void rnn_kernel(
    const float* __restrict__ bih0, const float* __restrict__ bhh0,
    const float* __restrict__ Whh0, const float* __restrict__ Wih0,
    const float* __restrict__ Wih1, const float* __restrict__ Whh1,
    const float* __restrict__ bih1, const float* __restrict__ bhh1,
    const float* __restrict__ Wcls, const float* __restrict__ bcls,
    float* __restrict__ out, float* ws) {
  extern __shared__ float smem[];
  f4* w4 = (f4*)smem;                    // 4096 f4 = 64 KB: [Whh0|Wih1|Whh1|Wih0] x 4 rows x 256 f4
  float* part = smem + 16384;            // 4096 floats: [kg 16][row 8][b 32]
  float* prebuf = smem + 20480;          // 2048 floats: [kg 16][r 4][b 32]

  const int bid = blockIdx.x, tid = threadIdx.x;
  const int b = tid & 31, kg = tid >> 5;     // kg 0..15
  const int kq0 = kg * 16;                   // f4 k-base (64 k per kg)

  unsigned* flags = (unsigned*)(ws + FLAGS);
  unsigned* relc = flags + 8192;             // 8 release copies @ stride 32
  const f4* x4p = (const f4*)(ws + X4);

  // stage 16 weight rows (4 per matrix)
  {
    const f4* s0 = (const f4*)Whh0 + (size_t)(bid * 4) * 256;
    const f4* s1 = (const f4*)Wih1 + (size_t)(bid * 4) * 256;
    const f4* s2 = (const f4*)Whh1 + (size_t)(bid * 4) * 256;
    const f4* s3 = (const f4*)Wih0 + (size_t)(bid * 4) * 256;
    for (int i = tid; i < 1024; i += 512) {
      w4[i] = s0[i]; w4[1024 + i] = s1[i];
      w4[2048 + i] = s2[i]; w4[3072 + i] = s3[i];
    }
  }

  // reducer constants (tid<256): rj 0..7; rj<4 -> h0 col, rj>=4 -> h1 col
  const int rj = tid >> 5;
  const int jcol = bid * 4 + (rj & 3);
  float bias = 0.f;
  if (tid < 256)
    bias = (rj < 4) ? (bih0[jcol] + bhh0[jcol]) : (bih1[jcol] + bhh1[jcol]);

  float lg0 = 0.f, lg1 = 0.f;
  __syncthreads();  // weights staged

  // ---- prologue: prebuf for t=0 (coalesced x4 reads) ----
  {
    const f4* xq = x4p + (size_t)kq0 * 32 + b;   // t=0
    f4 xp[16];
    #pragma unroll
    for (int q = 0; q < 16; ++q) ld_x4(xp[q], xq + (size_t)q * 32);
    asm volatile("s_waitcnt vmcnt(0)");
    __builtin_amdgcn_sched_barrier(0xF4);
    f4 p0 = (f4)0.f, p1 = (f4)0.f, p2 = (f4)0.f, p3 = (f4)0.f;
    #pragma unroll
    for (int q = 0; q < 16; ++q) {
      p0 += w4[3072 + 0 * 256 + kq0 + q] * xp[q];
      p1 += w4[3072 + 1 * 256 + kq0 + q] * xp[q];
      p2 += w4[3072 + 2 * 256 + kq0 + q] * xp[q];
      p3 += w4[3072 + 3 * 256 + kq0 + q] * xp[q];
    }
    prebuf[(kg * 4 + 0) * 32 + b] = hsum(p0);
    prebuf[(kg * 4 + 1) * 32 + b] = hsum(p1);
    prebuf[(kg * 4 + 2) * 32 + b] = hsum(p2);
    prebuf[(kg * 4 + 3) * 32 + b] = hsum(p3);
  }

  for (int s = 0; s <= NT; ++s) {
    // ---- grid barrier for epoch s: one-hop release via 8 line copies ----
    if (bid == 0) {
      if (tid > 0 && tid < 256) {
        const unsigned* fp = &flags[tid * 32];
        while (ld_flag(fp) < (unsigned)s) {}
      }
      __syncthreads();
      if (tid < 8) st_cohu(&relc[tid * 32], (unsigned)s);
    } else {
      if (tid == 0) {
        const unsigned* rxp = &relc[(bid & 7) * 32];
        while (ld_flag(rxp) < (unsigned)s) {}
      }
      __syncthreads();
    }
    __builtin_amdgcn_sched_barrier(0);

    const int rp = s & 1;
    const bool l1act = (s >= 1);

    // Wcls prefetch (waves 2-3 only; pinned OLDER than counted h-load batch)
    float wc0 = 0.f, wc1 = 0.f;
    if (tid >= 128 && tid < 256) {
      const int t = l1act ? (s - 1) : 0;
      wc0 = Wcls[(size_t)t * 1024 + jcol];
      wc1 = Wcls[(size_t)524288 + (size_t)t * 1024 + jcol];
    }
    __builtin_amdgcn_sched_barrier(0);

    // ---- batched coherent h loads (32 in flight) ----
    const f4* pa = (const f4*)(ws + (rp ? H01 : H00)) + b;
    const f4* pb = (const f4*)(ws + (rp ? H11 : H10)) + b;
    f4 hA[16], hB[16], xv[16];
    #pragma unroll
    for (int q = 0; q < 16; ++q) ld_l2x4(hA[q], pa + (size_t)(kq0 + q) * 32);
    #pragma unroll
    for (int q = 0; q < 16; ++q) ld_l2x4(hB[q], pb + (size_t)(kq0 + q) * 32);

    f4 acc[8];
    #pragma unroll
    for (int r = 0; r < 8; ++r) acc[r] = (f4)0.f;

    asm volatile("s_waitcnt vmcnt(24)");      // hA[0..7] done (in-order retire)
    __builtin_amdgcn_sched_barrier(0xF4);
    #pragma unroll
    for (int q = 0; q < 8; ++q) {
      #pragma unroll
      for (int r = 0; r < 4; ++r) {
        acc[r]     += w4[r * 256 + kq0 + q] * hA[q];          // Whh0 -> h0
        acc[4 + r] += w4[1024 + r * 256 + kq0 + q] * hA[q];   // Wih1 -> h1
      }
    }
    asm volatile("s_waitcnt vmcnt(16)");      // hA[8..15] done
    __builtin_amdgcn_sched_barrier(0xF4);
    #pragma unroll
    for (int q = 8; q < 16; ++q) {
      #pragma unroll
      for (int r = 0; r < 4; ++r) {
        acc[r]     += w4[r * 256 + kq0 + q] * hA[q];
        acc[4 + r] += w4[1024 + r * 256 + kq0 + q] * hA[q];
      }
    }

    // issue next-step x loads (coalesced; newest 16)
    const int tn = (s + 1 < NT) ? (s + 1) : (NT - 1);
    {
      const f4* xq = x4p + (size_t)tn * 8192 + (size_t)kq0 * 32 + b;
      #pragma unroll
      for (int q = 0; q < 16; ++q) ld_x4(xv[q], xq + (size_t)q * 32);
    }

    asm volatile("s_waitcnt vmcnt(16)");      // hB done (x are the 16 newest)
    __builtin_amdgcn_sched_barrier(0xF4);
    #pragma unroll
    for (int q = 0; q < 16; ++q) {
      #pragma unroll
      for (int r = 0; r < 4; ++r)
        acc[4 + r] += w4[2048 + r * 256 + kq0 + q] * hB[q];   // Whh1 -> h1
    }

    #pragma unroll
    for (int r = 0; r < 8; ++r)
      part[(kg * 8 + r) * 32 + b] = hsum(acc[r]);
    __syncthreads();   // also drains xv loads (vmcnt 0 at barrier)

    // ---- reduce + tanh + state store ----
    float hv1 = 0.f;
    if (tid < 256) {
      if (rj < 4) {
        if (s < NT) {
          float sum = bias;
          #pragma unroll
          for (int k = 0; k < 16; ++k) sum += part[(k * 8 + rj) * 32 + b];
          #pragma unroll
          for (int k = 0; k < 16; ++k) sum += prebuf[(k * 4 + rj) * 32 + b];
          float hv = tanhf(sum);
          float* dst = ws + (rp ? H00 : H01);
          st_cohf(dst + (bid * 128 + b * 4 + rj), hv);
          if (s == NT - 1) out[64 + (size_t)b * 1024 + jcol] = hv;
        }
      } else if (l1act) {
        const int r1 = rj - 4;
        float sum = bias;
        #pragma unroll
        for (int k = 0; k < 16; ++k) sum += part[(k * 8 + 4 + r1) * 32 + b];
        hv1 = tanhf(sum);
        float* dst = ws + (rp ? H10 : H11);
        st_cohf(dst + (bid * 128 + b * 4 + r1), hv1);
        if (s == NT) out[64 + 32768 + (size_t)b * 1024 + jcol] = hv1;
      }
    }
    __syncthreads();  // drains h stores before flag publish
    if (tid == 0) st_cohu(&flags[bid * 32], (unsigned)(s + 1));

    // ---- off-critical-path work during other blocks' barrier wait ----
    if (tid >= 128 && tid < 256 && l1act) {
      lg0 = fmaf(hv1, wc0, lg0);
      lg1 = fmaf(hv1, wc1, lg1);
    }
    {  // input-projection partials for t = tn
      f4 p0 = (f4)0.f, p1 = (f4)0.f, p2 = (f4)0.f, p3 = (f4)0.f;
      #pragma unroll
      for (int q = 0; q < 16; ++q) {
        p0 += w4[3072 + 0 * 256 + kq0 + q] * xv[q];
        p1 += w4[3072 + 1 * 256 + kq0 + q] * xv[q];
        p2 += w4[3072 + 2 * 256 + kq0 + q] * xv[q];
        p3 += w4[3072 + 3 * 256 + kq0 + q] * xv[q];
      }
      prebuf[(kg * 4 + 0) * 32 + b] = hsum(p0);
      prebuf[(kg * 4 + 1) * 32 + b] = hsum(p1);
      prebuf[(kg * 4 + 2) * 32 + b] = hsum(p2);
      prebuf[(kg * 4 + 3) * 32 + b] = hsum(p3);
    }
  }

  // ---- epilogue: classifier ----
  if (tid >= 128 && tid < 256) {
    const int r1 = rj - 4;
    part[r1 * 64 + b] = lg0;
    part[r1 * 64 + 32 + b] = lg1;
  }
  __syncthreads();
  if (tid < 64) {
    const int c = tid >> 5, bb = tid & 31;
    float v = 0.f;
    #pragma unroll
    for (int r1 = 0; r1 < 4; ++r1) v += part[r1 * 64 + c * 32 + bb];
    st_cohf(&ws[PLOG + (size_t)bid * 64 + c * 32 + bb], v);
  }
  __syncthreads();  // drain plog stores
  if (tid == 0) st_cohu(&flags[bid * 32], 600u);

  if (bid == 0) {
    if (tid > 0 && tid < 256) {
      const unsigned* fp = &flags[tid * 32];
      while (ld_flag(fp) < 600u) {}
    }
    __syncthreads();
    __builtin_amdgcn_sched_barrier(0);
    if (tid < 256) {
      const int g = tid >> 6, pair = tid & 63;  // g 0..3
      float v = 0.f;
      for (int blk = g; blk < 256; blk += 4)
        v += __hip_atomic_load(&ws[PLOG + (size_t)blk * 64 + pair],
                               __ATOMIC_RELAXED, __HIP_MEMORY_SCOPE_AGENT);
      part[tid] = v;
    }
    __syncthreads();
    if (tid < 64) {
      float s2 = bcls[tid >> 5];
      #pragma unroll
      for (int g = 0; g < 4; ++g) s2 += part[g * 64 + tid];
      out[(size_t)(tid & 31) * 2 + (tid >> 5)] = s2;  // logits [B,C]
    }
  }
}

extern "C" void kernel_launch(void* const* d_in, const int* in_sizes, int n_in,
                              void* d_out, int out_size, void* d_ws, size_t ws_size,
                              hipStream_t stream) {
  const float* x    = (const float*)d_in[0];
  const float* h0   = (const float*)d_in[1];
  const float* Wih0 = (const float*)d_in[2];
  const float* Whh0 = (const float*)d_in[3];
  const float* bih0 = (const float*)d_in[4];
  const float* bhh0 = (const float*)d_in[5];
  const float* Wih1 = (const float*)d_in[6];
  const float* Whh1 = (const float*)d_in[7];
  const float* bih1 = (const float*)d_in[8];
  const float* bhh1 = (const float*)d_in[9];
  const float* Wcls = (const float*)d_in[10];
  const float* bcls = (const float*)d_in[11];
  float* out = (float*)d_out;
  float* ws  = (float*)d_ws;

  hipFuncSetAttribute((const void*)rnn_kernel,
                      hipFuncAttributeMaxDynamicSharedMemorySize, 90112);

  hipLaunchKernelGGL(init_kernel, dim3(256), dim3(256), 0, stream, h0, ws);
  hipLaunchKernelGGL(xpose_kernel, dim3(512), dim3(256), 0, stream, x, ws);

  void* args[] = { (void*)&bih0, (void*)&bhh0, (void*)&Whh0, (void*)&Wih0,
                   (void*)&Wih1, (void*)&Whh1, (void*)&bih1, (void*)&bhh1,
                   (void*)&Wcls, (void*)&bcls, (void*)&out, (void*)&ws };
  hipLaunchCooperativeKernel((void*)rnn_kernel, dim3(256), dim3(512), args,
                             90112, stream);
}